// Round 2
// baseline (97.437 us; speedup 1.0000x reference)
//
#include <hip/hip_runtime.h>

// BoxRenderLoss: B box pairs, FP=100 fragment samples, BP=100 boundary samples.
// loss = [ sum_f min_p |boxfrag_f - tgtpt_p|^2 * outside(boxfrag_f, tgt)
//        + sum_f min_p |tgtfrag_f - boxpt_p|^2 * outside(tgtfrag_f, box) ] / (2*B*FP)

constexpr int BP = 100;   // 4 * BSTEP(25)
constexpr int FP = 100;   // FSTEP(10)^2

__global__ __launch_bounds__(256) void box_loss_partial(
    const float4* __restrict__ boxes, const float4* __restrict__ targets,
    float* __restrict__ partials)
{
    const int b = blockIdx.x;
    const float4 bx = boxes[b];
    const float4 tg = targets[b];

    __shared__ float2 tpts[BP];   // target boundary points (for box-fragment direction)
    __shared__ float2 bpts[BP];   // box boundary points (for target-fragment direction)

    const int t = threadIdx.x;

    // Boundary sample (u,v) in unit square, index t:
    //  t <  50: g1: u in {0,1} (t/25), v = (t%25)/24
    //  t >= 50: g2: u = ((t-50)/2)/24, v in {0,1} ((t-50)%2)
    if (t < BP) {
        float u, v;
        if (t < 50) {
            u = (t / 25) ? 1.0f : 0.0f;
            v = (float)(t % 25) * (1.0f / 24.0f);
        } else {
            const int q = t - 50;
            u = (float)(q >> 1) * (1.0f / 24.0f);
            v = (q & 1) ? 1.0f : 0.0f;
        }
        tpts[t] = make_float2(fmaf(u, tg.z - tg.x, tg.x), fmaf(v, tg.w - tg.y, tg.y));
        bpts[t] = make_float2(fmaf(u, bx.z - bx.x, bx.x), fmaf(v, bx.w - bx.y, bx.y));
    }
    __syncthreads();

    float val = 0.0f;
    if (t < 2 * FP) {
        const int d = (t >= FP);          // 0: box fragment vs target; 1: target fragment vs box
        const int f = d ? t - FP : t;
        const float fu = (float)(f / 10) * (1.0f / 9.0f);
        const float fv = (float)(f % 10) * (1.0f / 9.0f);
        const float4 s = d ? tg : bx;     // source box (fragment lives here)
        const float4 o = d ? bx : tg;     // other box (inside/outside test)
        const float px = fmaf(fu, s.z - s.x, s.x);
        const float py = fmaf(fv, s.w - s.y, s.y);

        // outside = NOT (px-o.x>=0 && py-o.y>=0 && o.z-px>=0 && o.w-py>=0)
        const bool outside = (px < o.x) || (py < o.y) || (px > o.z) || (py > o.w);
        if (outside) {
            const float2* __restrict__ pts = d ? bpts : tpts;
            float m = 3.402823466e+38f;
            #pragma unroll 10
            for (int p = 0; p < BP; ++p) {
                const float dx = px - pts[p].x;
                const float dy = py - pts[p].y;
                m = fminf(m, fmaf(dx, dx, dy * dy));
            }
            val = m;   // mask==1; inside case contributes exactly 0
        }
    }

    // block reduction: wave64 shuffle + 4-way LDS
    for (int off = 32; off > 0; off >>= 1) val += __shfl_down(val, off, 64);
    __shared__ float wsum[4];
    if ((t & 63) == 0) wsum[t >> 6] = val;
    __syncthreads();
    if (t == 0) partials[b] = wsum[0] + wsum[1] + wsum[2] + wsum[3];
}

__global__ __launch_bounds__(256) void box_loss_reduce(
    const float* __restrict__ partials, float* __restrict__ out,
    int nb, float scale)
{
    const int t = threadIdx.x;
    float s = 0.0f;
    for (int i = t; i < nb; i += 256) s += partials[i];
    for (int off = 32; off > 0; off >>= 1) s += __shfl_down(s, off, 64);
    __shared__ float wsum[4];
    if ((t & 63) == 0) wsum[t >> 6] = s;
    __syncthreads();
    if (t == 0) out[0] = (wsum[0] + wsum[1] + wsum[2] + wsum[3]) * scale;
}

extern "C" void kernel_launch(void* const* d_in, const int* in_sizes, int n_in,
                              void* d_out, int out_size, void* d_ws, size_t ws_size,
                              hipStream_t stream) {
    const float4* boxes   = (const float4*)d_in[0];
    const float4* targets = (const float4*)d_in[1];
    const int B = in_sizes[0] / 4;

    float* partials = (float*)d_ws;   // B floats of scratch
    box_loss_partial<<<B, 256, 0, stream>>>(boxes, targets, partials);

    const float scale = 1.0f / (2.0f * (float)B * (float)FP);
    box_loss_reduce<<<1, 256, 0, stream>>>(partials, (float*)d_out, B, scale);
}

// Round 4
// 57.881 us; speedup vs baseline: 1.6834x; 1.6834x over previous
//
#include <hip/hip_runtime.h>

// BoxRenderLoss, closed-form edge-distance version.
// The 100 boundary samples = 4 axis-aligned edges x 25 evenly spaced points.
// min over samples of |p-q|^2 = min over 4 edges of perp^2 + (along - nearest_sample)^2,
// nearest sample index = clamp(rint(24*r/w), 0, 24)  (exact argmin; ties value-equal).
// Vertical edges share the along-y term, horizontal edges share along-x.

constexpr int FP = 100;           // 10x10 fragment grid
constexpr int QUADS_PER_BOX = 50; // 200 items (2 directions x 100 fragments) / 4 per thread

__global__ __launch_bounds__(256) void box_loss_partial(
    const float4* __restrict__ boxes, const float4* __restrict__ targets,
    float* __restrict__ partials, int B)
{
    const int gtid = blockIdx.x * 256 + threadIdx.x;   // quad index
    float acc = 0.0f;

    if (gtid < B * QUADS_PER_BOX) {
        const int b  = gtid / QUADS_PER_BOX;
        const int q  = gtid - b * QUADS_PER_BOX;
        const int j0 = q * 4;                 // item in [0,200): 4 consecutive, same direction
        const int d  = (j0 >= FP);            // 0: box-frag vs target; 1: target-frag vs box

        const float4 bx = boxes[b];
        const float4 tg = targets[b];
        const float4 s = d ? tg : bx;         // fragment source box
        const float4 o = d ? bx : tg;         // other box (outside test + boundary)

        const float swx = s.z - s.x, swy = s.w - s.y;
        const float owx = o.z - o.x, owy = o.w - o.y;
        const float iwx = 24.0f / owx,          iwy = 24.0f / owy;   // inf/nan ok (clamped)
        const float wx24 = owx * (1.0f/24.0f),  wy24 = owy * (1.0f/24.0f);

        const int f0 = j0 - d * FP;           // fragment index base
        #pragma unroll
        for (int k = 0; k < 4; ++k) {
            const int f = f0 + k;
            const float fu = (float)(f / 10) * (1.0f/9.0f);
            const float fv = (float)(f % 10) * (1.0f/9.0f);
            const float px = fmaf(fu, swx, s.x);
            const float py = fmaf(fv, swy, s.y);
            const float rx = px - o.x, ry = py - o.y;

            // outside = NOT(rx>=0 && ry>=0 && o.z-px>=0 && o.w-py>=0)
            const bool outside = (rx < 0.0f) || (ry < 0.0f) || (px > o.z) || (py > o.w);
            if (outside) {
                float tx = rintf(rx * iwx); tx = fminf(fmaxf(tx, 0.0f), 24.0f);
                float ty = rintf(ry * iwy); ty = fminf(fmaxf(ty, 0.0f), 24.0f);
                const float dax = fmaf(-tx, wx24, rx);   // along-x residual to nearest sample
                const float day = fmaf(-ty, wy24, ry);   // along-y residual
                const float ax = dax * dax, ay = day * day;
                const float ex0 = rx * rx;
                const float ex1 = (rx - owx) * (rx - owx);
                const float ey0 = ry * ry;
                const float ey1 = (ry - owy) * (ry - owy);
                // 4 edges: x=lo, x=hi (share ay); y=lo, y=hi (share ax)
                acc += fminf(fminf(ex0 + ay, ex1 + ay), fminf(ax + ey0, ax + ey1));
            }
        }
    }

    // block reduction: wave64 shuffle + 4-way LDS
    for (int off = 32; off > 0; off >>= 1) acc += __shfl_down(acc, off, 64);
    __shared__ float wsum[4];
    const int t = threadIdx.x;
    if ((t & 63) == 0) wsum[t >> 6] = acc;
    __syncthreads();
    if (t == 0) partials[blockIdx.x] = wsum[0] + wsum[1] + wsum[2] + wsum[3];
}

__global__ __launch_bounds__(256) void box_loss_reduce(
    const float* __restrict__ partials, float* __restrict__ out,
    int nb, float scale)
{
    const int t = threadIdx.x;
    float s = 0.0f;
    for (int i = t; i < nb; i += 256) s += partials[i];
    for (int off = 32; off > 0; off >>= 1) s += __shfl_down(s, off, 64);
    __shared__ float wsum[4];
    if ((t & 63) == 0) wsum[t >> 6] = s;
    __syncthreads();
    if (t == 0) out[0] = (wsum[0] + wsum[1] + wsum[2] + wsum[3]) * scale;
}

extern "C" void kernel_launch(void* const* d_in, const int* in_sizes, int n_in,
                              void* d_out, int out_size, void* d_ws, size_t ws_size,
                              hipStream_t stream) {
    const float4* boxes   = (const float4*)d_in[0];
    const float4* targets = (const float4*)d_in[1];
    const int B = in_sizes[0] / 4;

    const int nthreads = B * QUADS_PER_BOX;        // 204800 for B=4096
    const int nblocks  = (nthreads + 255) / 256;   // 800

    float* partials = (float*)d_ws;
    box_loss_partial<<<nblocks, 256, 0, stream>>>(boxes, targets, partials, B);

    const float scale = 1.0f / (2.0f * (float)B * (float)FP);
    box_loss_reduce<<<1, 256, 0, stream>>>(partials, (float*)d_out, nblocks, scale);
}